// Round 1
// baseline (59.093 us; speedup 1.0000x reference)
//
#include <hip/hip_runtime.h>

// out[i] = cos^4( dot(x[i,:], W[0,:]) + b[0] )
//
// Derivation (Heisenberg picture): measured op is Z on wire 0; wire 0 is only
// ever a CNOT *control*, so Chain† Z0 Chain = Z0, and every Y0 branch produced
// by RX conjugation picks up an X-string on wires >=1 that never cancels
// (RX keeps X invariant; CNOT-chain conjugation maps X-strings to X-strings).
// Only the pure-Z0 branch survives <0..0|.|0..0>, with coefficient
// cos(theta0)^DEPTH = cos^4(theta0).  Verified by hand at n=2, DEPTH=2.

#define K 512          // feature dim
#define WAVES_PER_BLOCK 4

__global__ __launch_bounds__(256) void qg_expval_kernel(
    const float* __restrict__ x,   // [B, 512]
    const float* __restrict__ W,   // [12, 512] — only row 0 used
    const float* __restrict__ b,   // [12]      — only b[0] used
    float* __restrict__ out,       // [B]
    int B)
{
    const int wave = threadIdx.x >> 6;
    const int lane = threadIdx.x & 63;
    const int row  = blockIdx.x * WAVES_PER_BLOCK + wave;
    if (row >= B) return;

    const float4* xr = (const float4*)(x + (size_t)row * K);
    const float4* w4 = (const float4*)W;

    // 512 floats per row = 64 lanes * 2 * float4, fully coalesced 16B/lane
    float4 a0 = xr[lane];
    float4 a1 = xr[64 + lane];
    float4 w0 = w4[lane];
    float4 w1 = w4[64 + lane];

    float p = a0.x * w0.x + a0.y * w0.y + a0.z * w0.z + a0.w * w0.w
            + a1.x * w1.x + a1.y * w1.y + a1.z * w1.z + a1.w * w1.w;

    // wave-64 butterfly reduction
    #pragma unroll
    for (int off = 32; off > 0; off >>= 1)
        p += __shfl_xor(p, off, 64);

    if (lane == 0) {
        float th = p + b[0];
        float c  = cosf(th);
        float c2 = c * c;
        out[row] = c2 * c2;
    }
}

extern "C" void kernel_launch(void* const* d_in, const int* in_sizes, int n_in,
                              void* d_out, int out_size, void* d_ws, size_t ws_size,
                              hipStream_t stream) {
    const float* x = (const float*)d_in[0];   // [B, 512]
    const float* W = (const float*)d_in[1];   // [12, 512]
    const float* b = (const float*)d_in[2];   // [12]
    float* out = (float*)d_out;               // [B]

    const int B = in_sizes[0] / K;            // 4096
    const int rows_per_block = WAVES_PER_BLOCK;
    const int grid = (B + rows_per_block - 1) / rows_per_block;

    qg_expval_kernel<<<grid, 256, 0, stream>>>(x, W, b, out, B);
}